// Round 15
// baseline (204.937 us; speedup 1.0000x reference)
//
#include <hip/hip_runtime.h>
#include <hip/hip_bf16.h>

// CARAFE-style SAU. Round 20: fused kernel at 512 threads (8 waves).
//  - R19: 49.4us, occupancy grid-limited at 2 blocks/CU x 4 waves; barriers
//    unhidable. Now 8 waves/block (same grid, same per-thread registers):
//    16 waves/CU, half the phase-D barriers (chunks of 32 ch x 4).
//  - Phase A: 8 waves x 32px*16co (36 MFMA each). Phase B/C: waves 0-3 only
//    (barriers outside the if). Phase D: cg in [0,8), 4 chunks.
//  - LDS 69.1 KB (kls 25.6 + xls[32][5][68]); 2 blocks/CU unchanged.
//  - FMA order/operands bit-identical (absmax must stay 0.001953125).
//  - conv1/w_all byte-identical. 3 dispatches total.
// N=8, Cin=128, H=W=64, Cmid=64, NK=100, K=5, S=2.

typedef __attribute__((ext_vector_type(8))) short short8;
typedef __attribute__((ext_vector_type(4))) float f32x4;

static __device__ __forceinline__ short bf16_bits(float v) {
    __hip_bfloat16 h = __float2bfloat16(v);
    return __builtin_bit_cast(short, h);
}

// ---------------- merged weight prep ----------------
__global__ void w_all(const float* __restrict__ w_enc, const float* __restrict__ w_g1,
                      const float* __restrict__ w_kp, const float* __restrict__ w_g2,
                      __hip_bfloat16* __restrict__ wtt, __hip_bfloat16* __restrict__ wgt,
                      __hip_bfloat16* __restrict__ wkpt, __hip_bfloat16* __restrict__ wg2t) {
    int idx = blockIdx.x * 256 + threadIdx.x;
    if (idx < 73728) {
        int j = idx & 7, lane = (idx >> 3) & 63, nt = (idx >> 9) & 3, rest = idx >> 11;
        int kc = rest & 3, tap = rest >> 2;
        int co = nt * 16 + (lane & 15), ci = kc * 32 + (lane >> 4) * 8 + j;
        wtt[idx] = __float2bfloat16(w_enc[(co * 128 + ci) * 9 + tap]);
    } else if (idx < 110592) {
        int local = idx - 73728;
        int j = local & 7, lane = (local >> 3) & 63, nt = (local >> 9) & 3, rest = local >> 11;
        int kc = rest & 1, tap = rest >> 1;
        int co = nt * 16 + (lane & 15), ci = kc * 32 + (lane >> 4) * 8 + j;
        wgt[local] = __float2bfloat16(w_g1[(co * 64 + ci) * 9 + tap]);
    } else if (idx < 117760) {
        int local = idx - 110592;
        int co = local >> 6, ci = local & 63;
        float a = co < 100 ? w_kp[co * 64 + ci] : 0.f;
        float b = co < 100 ? w_g2[co * 64 + ci] : 0.f;
        wkpt[local] = __float2bfloat16(a);
        wg2t[local] = __float2bfloat16(b);
    }
}

// ---------------- conv1: stage f32 x directly, single-barrier MFMA ----------------
__global__ __launch_bounds__(256, 2) void conv1_tiled(
    const float* __restrict__ x, const __hip_bfloat16* __restrict__ wb,
    const float* __restrict__ bias, const float* __restrict__ gamma,
    const float* __restrict__ beta, const float* __restrict__ mean,
    const float* __restrict__ var, __hip_bfloat16* __restrict__ outp)
{
    constexpr int CIN = 128, KC = 4, CINP = 132;
    __shared__ short xs[3 * 66 * CINP];
    const int blk = blockIdx.x, h = blk & 63, n = blk >> 6;
    const int tid = threadIdx.x;
    const int lane = tid & 63, wave = tid >> 6;
    const int m = lane & 15, q = lane >> 4;
    const int mp = wave & 1, np = wave >> 1;

    if (tid < 96) {
        int c8 = tid & 15, side = (tid >> 4) & 1, r = tid >> 5;
        int col = side ? 65 : 0;
        *(short8*)&xs[(r * 66 + col) * CINP + c8 * 8] = (short8){0, 0, 0, 0, 0, 0, 0, 0};
    }
    for (int idx = tid; idx < 3072; idx += 256) {
        int w4 = idx & 15, ci2 = (idx >> 4) & 63, r = idx >> 10;
        int ci = ci2 * 2;
        int sr = h + r - 1;
        f32x4 v0 = {0.f, 0.f, 0.f, 0.f}, v1 = {0.f, 0.f, 0.f, 0.f};
        if ((unsigned)sr < 64u) {
            const float* xp0 = &x[((n * 128 + ci) * 64 + sr) * 64 + w4 * 4];
            v0 = *(const f32x4*)xp0;
            v1 = *(const f32x4*)(xp0 + 4096);
        }
        short* dst = &xs[(r * 66 + 1 + w4 * 4) * CINP + ci];
        #pragma unroll
        for (int d = 0; d < 4; ++d) {
            int pk = (int)(unsigned short)bf16_bits(v0[d]) |
                     ((int)(unsigned short)bf16_bits(v1[d]) << 16);
            *(int*)(dst + d * CINP) = pk;
        }
    }
    __syncthreads();

    f32x4 acc00 = {0.f, 0.f, 0.f, 0.f}, acc01 = {0.f, 0.f, 0.f, 0.f};
    f32x4 acc10 = {0.f, 0.f, 0.f, 0.f}, acc11 = {0.f, 0.f, 0.f, 0.f};
    const short* wgb = (const short*)wb + lane * 8;
    const int arow = mp * 32 + m;

    #pragma unroll
    for (int kh = 0; kh < 3; ++kh) {
        #pragma unroll
        for (int kw = 0; kw < 3; ++kw) {
            #pragma unroll
            for (int kc = 0; kc < KC; ++kc) {
                const short* ap = &xs[(kh * 66 + arow + kw) * CINP + kc * 32 + q * 8];
                short8 a0 = *(const short8*)ap;
                short8 a1 = *(const short8*)(ap + 16 * CINP);
                const int tap = kh * 3 + kw;
                const short* bp = wgb + (((tap * KC + kc) * 4 + np * 2) << 9);
                short8 b0 = *(const short8*)bp;
                short8 b1 = *(const short8*)(bp + 512);
                acc00 = __builtin_amdgcn_mfma_f32_16x16x32_bf16(a0, b0, acc00, 0, 0, 0);
                acc01 = __builtin_amdgcn_mfma_f32_16x16x32_bf16(a0, b1, acc01, 0, 0, 0);
                acc10 = __builtin_amdgcn_mfma_f32_16x16x32_bf16(a1, b0, acc10, 0, 0, 0);
                acc11 = __builtin_amdgcn_mfma_f32_16x16x32_bf16(a1, b1, acc11, 0, 0, 0);
            }
        }
    }

    float scv[2], shv[2];
    #pragma unroll
    for (int j = 0; j < 2; ++j) {
        const int c = np * 32 + j * 16 + m;
        float inv = rsqrtf(var[c] + 1e-5f);
        scv[j] = gamma[c] * inv;
        shv[j] = (bias[c] - mean[c]) * scv[j] + beta[c];
    }
    const f32x4* accs[2][2] = {{&acc00, &acc01}, {&acc10, &acc11}};
    #pragma unroll
    for (int i = 0; i < 2; ++i) {
        #pragma unroll
        for (int j = 0; j < 2; ++j) {
            const int c = np * 32 + j * 16 + m;
            const f32x4 a = *accs[i][j];
            #pragma unroll
            for (int r = 0; r < 4; ++r) {
                const int px = mp * 32 + i * 16 + q * 4 + r;
                float ov = fmaxf(fmaf(a[r], scv[j], shv[j]), 0.f);
                outp[(((n * 66 + h + 1) * 66) + px + 1) * 64 + c] = __float2bfloat16(ov);
            }
        }
    }
}

// ---------------- fused conv2 + predictor + softmax + reassembly (512 thr) ----------------
__global__ __launch_bounds__(512, 4) void conv2_reassembly(
    const __hip_bfloat16* __restrict__ cbf, const __hip_bfloat16* __restrict__ wb,
    const float* __restrict__ b_g1,
    const __hip_bfloat16* __restrict__ wkpt, const __hip_bfloat16* __restrict__ wg2t,
    const float* __restrict__ bkp, const float* __restrict__ bg2,
    const float* __restrict__ x, float* __restrict__ out)
{
    constexpr int CIN = 64, KC = 2, NC8 = 8, CINP = 68;
    // union carve: phase1 = xs(26928B)+g1s(8704B); phase2 = kls(25600B)+xls(43520B)
    __shared__ __align__(16) char smem[69120];
    short* xs  = (short*)smem;                  // [3*66][68]
    short* g1s = (short*)(smem + 26928);        // [64][68]
    float (*kls)[4][64] = (float(*)[4][64])smem;           // [25][4][64]
    float (*xls)[5][68] = (float(*)[5][68])(smem + 25600); // [32][5][68]

    const int blk = blockIdx.x, h = blk & 63, n = blk >> 6;
    const int tid = threadIdx.x;
    const int lane = tid & 63, wave = tid >> 6;   // wave in [0,8)
    const int m = lane & 15, q = lane >> 4;

    // stage content rows h..h+2 (padded coords); zero the border pixels
    const short* xg = (const short*)cbf + ((n * 66 + h) * 66) * CIN;
    for (int idx = tid; idx < 3 * 66 * NC8; idx += 512) {
        int p = idx >> 3;
        int c8 = idx & 7;
        int r = (p >= 132) ? 2 : (p >= 66 ? 1 : 0);
        int col = p - r * 66;
        int pr = h + r;
        short8 v = *(const short8*)(xg + idx * 8);
        if (pr == 0 || pr == 65 || col == 0 || col == 65)
            v = (short8){0, 0, 0, 0, 0, 0, 0, 0};
        *(short8*)&xs[p * CINP + c8 * 8] = v;
    }
    __syncthreads();

    // ---- phase A: conv2, 8 waves x (32 px x 16 co) ----
    {
        const int mp = wave & 1, np = wave >> 1;   // np in [0,4): co 16-block
        f32x4 acc00 = {0.f, 0.f, 0.f, 0.f}, acc10 = {0.f, 0.f, 0.f, 0.f};
        const short* wgb = (const short*)wb + lane * 8;
        const int arow = mp * 32 + m;
        #pragma unroll
        for (int kh = 0; kh < 3; ++kh) {
            #pragma unroll
            for (int kw = 0; kw < 3; ++kw) {
                #pragma unroll
                for (int kc = 0; kc < KC; ++kc) {
                    const short* ap = &xs[(kh * 66 + arow + kw) * CINP + kc * 32 + q * 8];
                    short8 a0 = *(const short8*)ap;
                    short8 a1 = *(const short8*)(ap + 16 * CINP);
                    const int tap = kh * 3 + kw;
                    const short* bp = wgb + (((tap * KC + kc) * 4 + np) << 9);
                    short8 b0 = *(const short8*)bp;
                    acc00 = __builtin_amdgcn_mfma_f32_16x16x32_bf16(a0, b0, acc00, 0, 0, 0);
                    acc10 = __builtin_amdgcn_mfma_f32_16x16x32_bf16(a1, b0, acc10, 0, 0, 0);
                }
            }
        }
        const int c = np * 16 + m;
        const float bb = b_g1[c];
        const f32x4* accs[2] = {&acc00, &acc10};
        #pragma unroll
        for (int i = 0; i < 2; ++i) {
            const f32x4 a = *accs[i];
            #pragma unroll
            for (int r = 0; r < 4; ++r) {
                const int px = mp * 32 + i * 16 + q * 4 + r;
                float ov = fmaxf(a[r] + bb, 0.f);
                g1s[px * 68 + c] = bf16_bits(ov);
            }
        }
    }
    __syncthreads();

    // ---- phase B: predictor GEMMs on waves 0-3 (wave = m-tile) ----
    float p[7][4];
    float rinv[4];
    if (wave < 4) {
        const int mt = wave;
        const short* aK = &xs[(66 + 1 + mt * 16 + m) * CINP];
        const short* aG = &g1s[(mt * 16 + m) * 68];
        const short* BK = (const short*)wkpt + m * 64;
        const short* BG = (const short*)wg2t + m * 64;

        f32x4 kacc[7], gacc[7];
        #pragma unroll
        for (int nt = 0; nt < 7; ++nt) {
            kacc[nt] = (f32x4){0.f, 0.f, 0.f, 0.f};
            gacc[nt] = (f32x4){0.f, 0.f, 0.f, 0.f};
        }
        #pragma unroll
        for (int ks = 0; ks < 2; ++ks) {
            short8 ak = *(const short8*)(aK + ks * 32 + q * 8);
            short8 ag = *(const short8*)(aG + ks * 32 + q * 8);
            #pragma unroll
            for (int nt = 0; nt < 7; ++nt) {
                short8 bk = *(const short8*)(BK + nt * 1024 + ks * 32 + q * 8);
                short8 bg = *(const short8*)(BG + nt * 1024 + ks * 32 + q * 8);
                kacc[nt] = __builtin_amdgcn_mfma_f32_16x16x32_bf16(ak, bk, kacc[nt], 0, 0, 0);
                gacc[nt] = __builtin_amdgcn_mfma_f32_16x16x32_bf16(ag, bg, gacc[nt], 0, 0, 0);
            }
        }

        float mxr[4] = {-1e30f, -1e30f, -1e30f, -1e30f};
        #pragma unroll
        for (int nt = 0; nt < 7; ++nt) {
            const int co = nt * 16 + m;
            const bool valid = co < 100;
            const float bk = valid ? bkp[co] : 0.f;
            const float bg = valid ? bg2[co] : 0.f;
            #pragma unroll
            for (int r = 0; r < 4; ++r) {
                float ka = kacc[nt][r] + bk;
                float ga = gacc[nt][r] + bg;
                float v = valid ? ka * (1.f / (1.f + __expf(-ga))) : -1e30f;
                p[nt][r] = v;
                mxr[r] = fmaxf(mxr[r], v);
            }
        }
        #pragma unroll
        for (int msk = 1; msk <= 8; msk <<= 1) {
            #pragma unroll
            for (int r = 0; r < 4; ++r)
                mxr[r] = fmaxf(mxr[r], __shfl_xor(mxr[r], msk, 64));
        }
        float sr[4] = {0.f, 0.f, 0.f, 0.f};
        #pragma unroll
        for (int nt = 0; nt < 7; ++nt) {
            #pragma unroll
            for (int r = 0; r < 4; ++r) {
                p[nt][r] = __expf(p[nt][r] - mxr[r]);
                sr[r] += p[nt][r];
            }
        }
        #pragma unroll
        for (int msk = 1; msk <= 8; msk <<= 1) {
            #pragma unroll
            for (int r = 0; r < 4; ++r)
                sr[r] += __shfl_xor(sr[r], msk, 64);
        }
        #pragma unroll
        for (int r = 0; r < 4; ++r) rinv[r] = 1.f / sr[r];
    }

    // ---- phase C: ker row -> LDS (xs/g1s dead after this barrier) ----
    __syncthreads();
    if (wave < 4) {
        const int mt = wave;
        #pragma unroll
        for (int nt = 0; nt < 7; ++nt) {
            const int co = nt * 16 + m;
            if (co < 100) {
                const int tap = co >> 2, quad = co & 3;
                #pragma unroll
                for (int r = 0; r < 4; ++r) {
                    const int px = mt * 16 + q * 4 + r;
                    kls[tap][quad][px] = p[nt][r] * rinv[r];
                }
            }
        }
    }

    // ---- T14 prefetch machinery (CT=32 over 512 threads: 5 f32x4 each) ----
    const int w = tid & 63, cg = tid >> 6;   // cg in [0,8)
    f32x4 pf[5];
    float pel = 0.f, per_ = 0.f;
    auto prefetch = [&](int c0v) {
        const float* xb = &x[(size_t)(n * 128 + c0v) * 4096];
        #pragma unroll
        for (int k = 0; k < 5; ++k) {
            int idx = tid + k * 512;
            int c = idx / 80, r2 = idx % 80;
            int rr = r2 / 16, c4 = r2 % 16;
            int srr = min(max(h - 2 + rr, 0), 63);
            pf[k] = *(const f32x4*)&xb[c * 4096 + srr * 64 + c4 * 4];
        }
        if (tid < 160) {
            int c = tid / 5, rr = tid % 5;
            int srr = min(max(h - 2 + rr, 0), 63);
            pel  = xb[c * 4096 + srr * 64 + 0];
            per_ = xb[c * 4096 + srr * 64 + 63];
        }
    };
    auto commit = [&]() {
        #pragma unroll
        for (int k = 0; k < 5; ++k) {
            int idx = tid + k * 512;
            int c = idx / 80, r2 = idx % 80;
            int rr = r2 / 16, c4 = r2 % 16;
            *(float2*)&xls[c][rr][2 + c4 * 4] = make_float2(pf[k][0], pf[k][1]);
            *(float2*)&xls[c][rr][4 + c4 * 4] = make_float2(pf[k][2], pf[k][3]);
        }
        if (tid < 160) {
            int c = tid / 5, rr = tid % 5;
            xls[c][rr][0] = pel;  xls[c][rr][1] = pel;
            xls[c][rr][66] = per_; xls[c][rr][67] = per_;
        }
    };

    prefetch(0);       // chunk-0 loads overlap the kls writes above
    commit();          // land them (xls not read before the next barrier)
    __syncthreads();

    // ---- phase D: 4 chunks of 32 channels; prefetch(c+1) under compute ----
    for (int chunk = 0; ; ++chunk) {
        if (chunk < 3) prefetch((chunk + 1) * 32);
        const int c0 = chunk * 32;
        float4 acc[4] = {{0.f, 0.f, 0.f, 0.f}, {0.f, 0.f, 0.f, 0.f},
                         {0.f, 0.f, 0.f, 0.f}, {0.f, 0.f, 0.f, 0.f}};
        #pragma unroll
        for (int i = 0; i < 5; ++i) {
            #pragma unroll
            for (int j = 0; j < 5; ++j) {
                const int t = i * 5 + j;
                const float kx = kls[t][0][w];
                const float ky = kls[t][1][w];
                const float kz = kls[t][2][w];
                const float kw_ = kls[t][3][w];
                #pragma unroll
                for (int cc = 0; cc < 4; ++cc) {
                    const float xv = xls[cg * 4 + cc][i][w + j];
                    acc[cc].x = fmaf(xv, kx, acc[cc].x);
                    acc[cc].y = fmaf(xv, ky, acc[cc].y);
                    acc[cc].z = fmaf(xv, kz, acc[cc].z);
                    acc[cc].w = fmaf(xv, kw_, acc[cc].w);
                }
            }
        }
        #pragma unroll
        for (int cc = 0; cc < 4; ++cc) {
            const int c = c0 + cg * 4 + cc;
            *(float2*)&out[((n * 128 + c) * 128 + 2 * h + 0) * 128 + 2 * w] =
                make_float2(acc[cc].x, acc[cc].y);
            *(float2*)&out[((n * 128 + c) * 128 + 2 * h + 1) * 128 + 2 * w] =
                make_float2(acc[cc].z, acc[cc].w);
        }
        if (chunk == 3) break;
        __syncthreads();   // all reads of xls done
        commit();          // land prefetched chunk
        __syncthreads();   // xls ready
    }
}

extern "C" void kernel_launch(void* const* d_in, const int* in_sizes, int n_in,
                              void* d_out, int out_size, void* d_ws, size_t ws_size,
                              hipStream_t stream) {
    const float* x     = (const float*)d_in[0];
    const float* w_enc = (const float*)d_in[1];
    const float* b_enc = (const float*)d_in[2];
    const float* gamma = (const float*)d_in[3];
    const float* beta  = (const float*)d_in[4];
    const float* mean  = (const float*)d_in[5];
    const float* var   = (const float*)d_in[6];
    const float* w_kp  = (const float*)d_in[7];
    const float* b_kp  = (const float*)d_in[8];
    const float* w_g1  = (const float*)d_in[9];
    const float* b_g1  = (const float*)d_in[10];
    const float* w_g2  = (const float*)d_in[11];
    const float* b_g2  = (const float*)d_in[12];
    float* out = (float*)d_out;

    // ws carve (ker eliminated)
    __hip_bfloat16* cbf  = (__hip_bfloat16*)d_ws;            // (N,66,66,64) bf16
    __hip_bfloat16* wtt  = cbf + 2230272;                    // conv1 B-frags (73728)
    __hip_bfloat16* wgt  = wtt + 73728;                      // conv2 B-frags (36864)
    __hip_bfloat16* wkpt = wgt + 36864;                      // [112][64] bf16
    __hip_bfloat16* wg2t = wkpt + 7168;                      // [112][64] bf16

    w_all<<<460, 256, 0, stream>>>(w_enc, w_g1, w_kp, w_g2, wtt, wgt, wkpt, wg2t);
    conv1_tiled<<<512, 256, 0, stream>>>(
        x, wtt, b_enc, gamma, beta, mean, var, cbf);
    conv2_reassembly<<<512, 512, 0, stream>>>(
        cbf, wgt, b_g1, wkpt, wg2t, b_kp, b_g2, x, out);
}

// Round 16
// 178.284 us; speedup vs baseline: 1.1495x; 1.1495x over previous
//
#include <hip/hip_runtime.h>
#include <hip/hip_bf16.h>

// CARAFE-style SAU. Round 21: R20's 8-wave fused kernel with the VGPR cap
// fixed. R20's __launch_bounds__(512,4) resolved to a 64-VGPR cap ->
// ~40 regs spilled (WRITE_SIZE 174MB, 91.8us). (512,2) caps at 128 >= the
// ~104 the kernel actually needs (R19 footprint).
//  - 8 waves/block, 512 blocks: 16 waves/CU, phase-D = 4 chunks x 32 ch
//    (half R19's barriers).
//  - Phase A: 8 waves x 32px*16co. Phase B/C: waves 0-3. T14 prefetch kept.
//  - FMA order/operands bit-identical (absmax must stay 0.001953125).
//  - conv1/w_all byte-identical. 3 dispatches total.
// N=8, Cin=128, H=W=64, Cmid=64, NK=100, K=5, S=2.

typedef __attribute__((ext_vector_type(8))) short short8;
typedef __attribute__((ext_vector_type(4))) float f32x4;

static __device__ __forceinline__ short bf16_bits(float v) {
    __hip_bfloat16 h = __float2bfloat16(v);
    return __builtin_bit_cast(short, h);
}

// ---------------- merged weight prep ----------------
__global__ void w_all(const float* __restrict__ w_enc, const float* __restrict__ w_g1,
                      const float* __restrict__ w_kp, const float* __restrict__ w_g2,
                      __hip_bfloat16* __restrict__ wtt, __hip_bfloat16* __restrict__ wgt,
                      __hip_bfloat16* __restrict__ wkpt, __hip_bfloat16* __restrict__ wg2t) {
    int idx = blockIdx.x * 256 + threadIdx.x;
    if (idx < 73728) {
        int j = idx & 7, lane = (idx >> 3) & 63, nt = (idx >> 9) & 3, rest = idx >> 11;
        int kc = rest & 3, tap = rest >> 2;
        int co = nt * 16 + (lane & 15), ci = kc * 32 + (lane >> 4) * 8 + j;
        wtt[idx] = __float2bfloat16(w_enc[(co * 128 + ci) * 9 + tap]);
    } else if (idx < 110592) {
        int local = idx - 73728;
        int j = local & 7, lane = (local >> 3) & 63, nt = (local >> 9) & 3, rest = local >> 11;
        int kc = rest & 1, tap = rest >> 1;
        int co = nt * 16 + (lane & 15), ci = kc * 32 + (lane >> 4) * 8 + j;
        wgt[local] = __float2bfloat16(w_g1[(co * 64 + ci) * 9 + tap]);
    } else if (idx < 117760) {
        int local = idx - 110592;
        int co = local >> 6, ci = local & 63;
        float a = co < 100 ? w_kp[co * 64 + ci] : 0.f;
        float b = co < 100 ? w_g2[co * 64 + ci] : 0.f;
        wkpt[local] = __float2bfloat16(a);
        wg2t[local] = __float2bfloat16(b);
    }
}

// ---------------- conv1: stage f32 x directly, single-barrier MFMA ----------------
__global__ __launch_bounds__(256, 2) void conv1_tiled(
    const float* __restrict__ x, const __hip_bfloat16* __restrict__ wb,
    const float* __restrict__ bias, const float* __restrict__ gamma,
    const float* __restrict__ beta, const float* __restrict__ mean,
    const float* __restrict__ var, __hip_bfloat16* __restrict__ outp)
{
    constexpr int CIN = 128, KC = 4, CINP = 132;
    __shared__ short xs[3 * 66 * CINP];
    const int blk = blockIdx.x, h = blk & 63, n = blk >> 6;
    const int tid = threadIdx.x;
    const int lane = tid & 63, wave = tid >> 6;
    const int m = lane & 15, q = lane >> 4;
    const int mp = wave & 1, np = wave >> 1;

    if (tid < 96) {
        int c8 = tid & 15, side = (tid >> 4) & 1, r = tid >> 5;
        int col = side ? 65 : 0;
        *(short8*)&xs[(r * 66 + col) * CINP + c8 * 8] = (short8){0, 0, 0, 0, 0, 0, 0, 0};
    }
    for (int idx = tid; idx < 3072; idx += 256) {
        int w4 = idx & 15, ci2 = (idx >> 4) & 63, r = idx >> 10;
        int ci = ci2 * 2;
        int sr = h + r - 1;
        f32x4 v0 = {0.f, 0.f, 0.f, 0.f}, v1 = {0.f, 0.f, 0.f, 0.f};
        if ((unsigned)sr < 64u) {
            const float* xp0 = &x[((n * 128 + ci) * 64 + sr) * 64 + w4 * 4];
            v0 = *(const f32x4*)xp0;
            v1 = *(const f32x4*)(xp0 + 4096);
        }
        short* dst = &xs[(r * 66 + 1 + w4 * 4) * CINP + ci];
        #pragma unroll
        for (int d = 0; d < 4; ++d) {
            int pk = (int)(unsigned short)bf16_bits(v0[d]) |
                     ((int)(unsigned short)bf16_bits(v1[d]) << 16);
            *(int*)(dst + d * CINP) = pk;
        }
    }
    __syncthreads();

    f32x4 acc00 = {0.f, 0.f, 0.f, 0.f}, acc01 = {0.f, 0.f, 0.f, 0.f};
    f32x4 acc10 = {0.f, 0.f, 0.f, 0.f}, acc11 = {0.f, 0.f, 0.f, 0.f};
    const short* wgb = (const short*)wb + lane * 8;
    const int arow = mp * 32 + m;

    #pragma unroll
    for (int kh = 0; kh < 3; ++kh) {
        #pragma unroll
        for (int kw = 0; kw < 3; ++kw) {
            #pragma unroll
            for (int kc = 0; kc < KC; ++kc) {
                const short* ap = &xs[(kh * 66 + arow + kw) * CINP + kc * 32 + q * 8];
                short8 a0 = *(const short8*)ap;
                short8 a1 = *(const short8*)(ap + 16 * CINP);
                const int tap = kh * 3 + kw;
                const short* bp = wgb + (((tap * KC + kc) * 4 + np * 2) << 9);
                short8 b0 = *(const short8*)bp;
                short8 b1 = *(const short8*)(bp + 512);
                acc00 = __builtin_amdgcn_mfma_f32_16x16x32_bf16(a0, b0, acc00, 0, 0, 0);
                acc01 = __builtin_amdgcn_mfma_f32_16x16x32_bf16(a0, b1, acc01, 0, 0, 0);
                acc10 = __builtin_amdgcn_mfma_f32_16x16x32_bf16(a1, b0, acc10, 0, 0, 0);
                acc11 = __builtin_amdgcn_mfma_f32_16x16x32_bf16(a1, b1, acc11, 0, 0, 0);
            }
        }
    }

    float scv[2], shv[2];
    #pragma unroll
    for (int j = 0; j < 2; ++j) {
        const int c = np * 32 + j * 16 + m;
        float inv = rsqrtf(var[c] + 1e-5f);
        scv[j] = gamma[c] * inv;
        shv[j] = (bias[c] - mean[c]) * scv[j] + beta[c];
    }
    const f32x4* accs[2][2] = {{&acc00, &acc01}, {&acc10, &acc11}};
    #pragma unroll
    for (int i = 0; i < 2; ++i) {
        #pragma unroll
        for (int j = 0; j < 2; ++j) {
            const int c = np * 32 + j * 16 + m;
            const f32x4 a = *accs[i][j];
            #pragma unroll
            for (int r = 0; r < 4; ++r) {
                const int px = mp * 32 + i * 16 + q * 4 + r;
                float ov = fmaxf(fmaf(a[r], scv[j], shv[j]), 0.f);
                outp[(((n * 66 + h + 1) * 66) + px + 1) * 64 + c] = __float2bfloat16(ov);
            }
        }
    }
}

// ---------------- fused conv2 + predictor + softmax + reassembly (512 thr) ----------------
__global__ __launch_bounds__(512, 2) void conv2_reassembly(
    const __hip_bfloat16* __restrict__ cbf, const __hip_bfloat16* __restrict__ wb,
    const float* __restrict__ b_g1,
    const __hip_bfloat16* __restrict__ wkpt, const __hip_bfloat16* __restrict__ wg2t,
    const float* __restrict__ bkp, const float* __restrict__ bg2,
    const float* __restrict__ x, float* __restrict__ out)
{
    constexpr int CIN = 64, KC = 2, NC8 = 8, CINP = 68;
    // union carve: phase1 = xs(26928B)+g1s(8704B); phase2 = kls(25600B)+xls(43520B)
    __shared__ __align__(16) char smem[69120];
    short* xs  = (short*)smem;                  // [3*66][68]
    short* g1s = (short*)(smem + 26928);        // [64][68]
    float (*kls)[4][64] = (float(*)[4][64])smem;           // [25][4][64]
    float (*xls)[5][68] = (float(*)[5][68])(smem + 25600); // [32][5][68]

    const int blk = blockIdx.x, h = blk & 63, n = blk >> 6;
    const int tid = threadIdx.x;
    const int lane = tid & 63, wave = tid >> 6;   // wave in [0,8)
    const int m = lane & 15, q = lane >> 4;

    // stage content rows h..h+2 (padded coords); zero the border pixels
    const short* xg = (const short*)cbf + ((n * 66 + h) * 66) * CIN;
    for (int idx = tid; idx < 3 * 66 * NC8; idx += 512) {
        int p = idx >> 3;
        int c8 = idx & 7;
        int r = (p >= 132) ? 2 : (p >= 66 ? 1 : 0);
        int col = p - r * 66;
        int pr = h + r;
        short8 v = *(const short8*)(xg + idx * 8);
        if (pr == 0 || pr == 65 || col == 0 || col == 65)
            v = (short8){0, 0, 0, 0, 0, 0, 0, 0};
        *(short8*)&xs[p * CINP + c8 * 8] = v;
    }
    __syncthreads();

    // ---- phase A: conv2, 8 waves x (32 px x 16 co) ----
    {
        const int mp = wave & 1, np = wave >> 1;   // np in [0,4): co 16-block
        f32x4 acc00 = {0.f, 0.f, 0.f, 0.f}, acc10 = {0.f, 0.f, 0.f, 0.f};
        const short* wgb = (const short*)wb + lane * 8;
        const int arow = mp * 32 + m;
        #pragma unroll
        for (int kh = 0; kh < 3; ++kh) {
            #pragma unroll
            for (int kw = 0; kw < 3; ++kw) {
                #pragma unroll
                for (int kc = 0; kc < KC; ++kc) {
                    const short* ap = &xs[(kh * 66 + arow + kw) * CINP + kc * 32 + q * 8];
                    short8 a0 = *(const short8*)ap;
                    short8 a1 = *(const short8*)(ap + 16 * CINP);
                    const int tap = kh * 3 + kw;
                    const short* bp = wgb + (((tap * KC + kc) * 4 + np) << 9);
                    short8 b0 = *(const short8*)bp;
                    acc00 = __builtin_amdgcn_mfma_f32_16x16x32_bf16(a0, b0, acc00, 0, 0, 0);
                    acc10 = __builtin_amdgcn_mfma_f32_16x16x32_bf16(a1, b0, acc10, 0, 0, 0);
                }
            }
        }
        const int c = np * 16 + m;
        const float bb = b_g1[c];
        const f32x4* accs[2] = {&acc00, &acc10};
        #pragma unroll
        for (int i = 0; i < 2; ++i) {
            const f32x4 a = *accs[i];
            #pragma unroll
            for (int r = 0; r < 4; ++r) {
                const int px = mp * 32 + i * 16 + q * 4 + r;
                float ov = fmaxf(a[r] + bb, 0.f);
                g1s[px * 68 + c] = bf16_bits(ov);
            }
        }
    }
    __syncthreads();

    // ---- phase B: predictor GEMMs on waves 0-3 (wave = m-tile) ----
    float p[7][4];
    float rinv[4];
    if (wave < 4) {
        const int mt = wave;
        const short* aK = &xs[(66 + 1 + mt * 16 + m) * CINP];
        const short* aG = &g1s[(mt * 16 + m) * 68];
        const short* BK = (const short*)wkpt + m * 64;
        const short* BG = (const short*)wg2t + m * 64;

        f32x4 kacc[7], gacc[7];
        #pragma unroll
        for (int nt = 0; nt < 7; ++nt) {
            kacc[nt] = (f32x4){0.f, 0.f, 0.f, 0.f};
            gacc[nt] = (f32x4){0.f, 0.f, 0.f, 0.f};
        }
        #pragma unroll
        for (int ks = 0; ks < 2; ++ks) {
            short8 ak = *(const short8*)(aK + ks * 32 + q * 8);
            short8 ag = *(const short8*)(aG + ks * 32 + q * 8);
            #pragma unroll
            for (int nt = 0; nt < 7; ++nt) {
                short8 bk = *(const short8*)(BK + nt * 1024 + ks * 32 + q * 8);
                short8 bg = *(const short8*)(BG + nt * 1024 + ks * 32 + q * 8);
                kacc[nt] = __builtin_amdgcn_mfma_f32_16x16x32_bf16(ak, bk, kacc[nt], 0, 0, 0);
                gacc[nt] = __builtin_amdgcn_mfma_f32_16x16x32_bf16(ag, bg, gacc[nt], 0, 0, 0);
            }
        }

        float mxr[4] = {-1e30f, -1e30f, -1e30f, -1e30f};
        #pragma unroll
        for (int nt = 0; nt < 7; ++nt) {
            const int co = nt * 16 + m;
            const bool valid = co < 100;
            const float bk = valid ? bkp[co] : 0.f;
            const float bg = valid ? bg2[co] : 0.f;
            #pragma unroll
            for (int r = 0; r < 4; ++r) {
                float ka = kacc[nt][r] + bk;
                float ga = gacc[nt][r] + bg;
                float v = valid ? ka * (1.f / (1.f + __expf(-ga))) : -1e30f;
                p[nt][r] = v;
                mxr[r] = fmaxf(mxr[r], v);
            }
        }
        #pragma unroll
        for (int msk = 1; msk <= 8; msk <<= 1) {
            #pragma unroll
            for (int r = 0; r < 4; ++r)
                mxr[r] = fmaxf(mxr[r], __shfl_xor(mxr[r], msk, 64));
        }
        float sr[4] = {0.f, 0.f, 0.f, 0.f};
        #pragma unroll
        for (int nt = 0; nt < 7; ++nt) {
            #pragma unroll
            for (int r = 0; r < 4; ++r) {
                p[nt][r] = __expf(p[nt][r] - mxr[r]);
                sr[r] += p[nt][r];
            }
        }
        #pragma unroll
        for (int msk = 1; msk <= 8; msk <<= 1) {
            #pragma unroll
            for (int r = 0; r < 4; ++r)
                sr[r] += __shfl_xor(sr[r], msk, 64);
        }
        #pragma unroll
        for (int r = 0; r < 4; ++r) rinv[r] = 1.f / sr[r];
    }

    // ---- phase C: ker row -> LDS (xs/g1s dead after this barrier) ----
    __syncthreads();
    if (wave < 4) {
        const int mt = wave;
        #pragma unroll
        for (int nt = 0; nt < 7; ++nt) {
            const int co = nt * 16 + m;
            if (co < 100) {
                const int tap = co >> 2, quad = co & 3;
                #pragma unroll
                for (int r = 0; r < 4; ++r) {
                    const int px = mt * 16 + q * 4 + r;
                    kls[tap][quad][px] = p[nt][r] * rinv[r];
                }
            }
        }
    }

    // ---- T14 prefetch machinery (CT=32 over 512 threads: 5 f32x4 each) ----
    const int w = tid & 63, cg = tid >> 6;   // cg in [0,8)
    f32x4 pf[5];
    float pel = 0.f, per_ = 0.f;
    auto prefetch = [&](int c0v) {
        const float* xb = &x[(size_t)(n * 128 + c0v) * 4096];
        #pragma unroll
        for (int k = 0; k < 5; ++k) {
            int idx = tid + k * 512;
            int c = idx / 80, r2 = idx % 80;
            int rr = r2 / 16, c4 = r2 % 16;
            int srr = min(max(h - 2 + rr, 0), 63);
            pf[k] = *(const f32x4*)&xb[c * 4096 + srr * 64 + c4 * 4];
        }
        if (tid < 160) {
            int c = tid / 5, rr = tid % 5;
            int srr = min(max(h - 2 + rr, 0), 63);
            pel  = xb[c * 4096 + srr * 64 + 0];
            per_ = xb[c * 4096 + srr * 64 + 63];
        }
    };
    auto commit = [&]() {
        #pragma unroll
        for (int k = 0; k < 5; ++k) {
            int idx = tid + k * 512;
            int c = idx / 80, r2 = idx % 80;
            int rr = r2 / 16, c4 = r2 % 16;
            *(float2*)&xls[c][rr][2 + c4 * 4] = make_float2(pf[k][0], pf[k][1]);
            *(float2*)&xls[c][rr][4 + c4 * 4] = make_float2(pf[k][2], pf[k][3]);
        }
        if (tid < 160) {
            int c = tid / 5, rr = tid % 5;
            xls[c][rr][0] = pel;  xls[c][rr][1] = pel;
            xls[c][rr][66] = per_; xls[c][rr][67] = per_;
        }
    };

    prefetch(0);       // chunk-0 loads overlap the kls writes above
    commit();          // land them (xls not read before the next barrier)
    __syncthreads();

    // ---- phase D: 4 chunks of 32 channels; prefetch(c+1) under compute ----
    for (int chunk = 0; ; ++chunk) {
        if (chunk < 3) prefetch((chunk + 1) * 32);
        const int c0 = chunk * 32;
        float4 acc[4] = {{0.f, 0.f, 0.f, 0.f}, {0.f, 0.f, 0.f, 0.f},
                         {0.f, 0.f, 0.f, 0.f}, {0.f, 0.f, 0.f, 0.f}};
        #pragma unroll
        for (int i = 0; i < 5; ++i) {
            #pragma unroll
            for (int j = 0; j < 5; ++j) {
                const int t = i * 5 + j;
                const float kx = kls[t][0][w];
                const float ky = kls[t][1][w];
                const float kz = kls[t][2][w];
                const float kw_ = kls[t][3][w];
                #pragma unroll
                for (int cc = 0; cc < 4; ++cc) {
                    const float xv = xls[cg * 4 + cc][i][w + j];
                    acc[cc].x = fmaf(xv, kx, acc[cc].x);
                    acc[cc].y = fmaf(xv, ky, acc[cc].y);
                    acc[cc].z = fmaf(xv, kz, acc[cc].z);
                    acc[cc].w = fmaf(xv, kw_, acc[cc].w);
                }
            }
        }
        #pragma unroll
        for (int cc = 0; cc < 4; ++cc) {
            const int c = c0 + cg * 4 + cc;
            *(float2*)&out[((n * 128 + c) * 128 + 2 * h + 0) * 128 + 2 * w] =
                make_float2(acc[cc].x, acc[cc].y);
            *(float2*)&out[((n * 128 + c) * 128 + 2 * h + 1) * 128 + 2 * w] =
                make_float2(acc[cc].z, acc[cc].w);
        }
        if (chunk == 3) break;
        __syncthreads();   // all reads of xls done
        commit();          // land prefetched chunk
        __syncthreads();   // xls ready
    }
}

extern "C" void kernel_launch(void* const* d_in, const int* in_sizes, int n_in,
                              void* d_out, int out_size, void* d_ws, size_t ws_size,
                              hipStream_t stream) {
    const float* x     = (const float*)d_in[0];
    const float* w_enc = (const float*)d_in[1];
    const float* b_enc = (const float*)d_in[2];
    const float* gamma = (const float*)d_in[3];
    const float* beta  = (const float*)d_in[4];
    const float* mean  = (const float*)d_in[5];
    const float* var   = (const float*)d_in[6];
    const float* w_kp  = (const float*)d_in[7];
    const float* b_kp  = (const float*)d_in[8];
    const float* w_g1  = (const float*)d_in[9];
    const float* b_g1  = (const float*)d_in[10];
    const float* w_g2  = (const float*)d_in[11];
    const float* b_g2  = (const float*)d_in[12];
    float* out = (float*)d_out;

    // ws carve (ker eliminated)
    __hip_bfloat16* cbf  = (__hip_bfloat16*)d_ws;            // (N,66,66,64) bf16
    __hip_bfloat16* wtt  = cbf + 2230272;                    // conv1 B-frags (73728)
    __hip_bfloat16* wgt  = wtt + 73728;                      // conv2 B-frags (36864)
    __hip_bfloat16* wkpt = wgt + 36864;                      // [112][64] bf16
    __hip_bfloat16* wg2t = wkpt + 7168;                      // [112][64] bf16

    w_all<<<460, 256, 0, stream>>>(w_enc, w_g1, w_kp, w_g2, wtt, wgt, wkpt, wg2t);
    conv1_tiled<<<512, 256, 0, stream>>>(
        x, wtt, b_enc, gamma, beta, mean, var, cbf);
    conv2_reassembly<<<512, 512, 0, stream>>>(
        cbf, wgt, b_g1, wkpt, wg2t, b_kp, b_g2, x, out);
}

// Round 17
// 168.437 us; speedup vs baseline: 1.2167x; 1.0585x over previous
//
#include <hip/hip_runtime.h>
#include <hip/hip_bf16.h>

// CARAFE-style SAU. Round 22: conv2_reassembly reverted to R19 (best, 49.4us);
// conv1 split into half-row blocks for 2x occupancy.
//  - R21 falsified the wide-block theory (8 waves, no spill: 61.7 vs 49.4).
//  - conv1: grid 1024 (n,h,half of 32px), LDS 26.9 KB, launch_bounds(256,4)
//    -> 4 blocks/CU, 16 waves/CU (was 2 blocks/8 waves); 72 MFMA/wave.
//    Staging: spans cover src cols [B,B+36), per-element lc in [0,34)
//    predicate; border col zeroed; row borders via sr predicate.
//  - Math bit-identical everywhere (absmax must stay 0.001953125).
// N=8, Cin=128, H=W=64, Cmid=64, NK=100, K=5, S=2.

typedef __attribute__((ext_vector_type(8))) short short8;
typedef __attribute__((ext_vector_type(4))) float f32x4;

static __device__ __forceinline__ short bf16_bits(float v) {
    __hip_bfloat16 h = __float2bfloat16(v);
    return __builtin_bit_cast(short, h);
}

// ---------------- merged weight prep ----------------
__global__ void w_all(const float* __restrict__ w_enc, const float* __restrict__ w_g1,
                      const float* __restrict__ w_kp, const float* __restrict__ w_g2,
                      __hip_bfloat16* __restrict__ wtt, __hip_bfloat16* __restrict__ wgt,
                      __hip_bfloat16* __restrict__ wkpt, __hip_bfloat16* __restrict__ wg2t) {
    int idx = blockIdx.x * 256 + threadIdx.x;
    if (idx < 73728) {
        int j = idx & 7, lane = (idx >> 3) & 63, nt = (idx >> 9) & 3, rest = idx >> 11;
        int kc = rest & 3, tap = rest >> 2;
        int co = nt * 16 + (lane & 15), ci = kc * 32 + (lane >> 4) * 8 + j;
        wtt[idx] = __float2bfloat16(w_enc[(co * 128 + ci) * 9 + tap]);
    } else if (idx < 110592) {
        int local = idx - 73728;
        int j = local & 7, lane = (local >> 3) & 63, nt = (local >> 9) & 3, rest = local >> 11;
        int kc = rest & 1, tap = rest >> 1;
        int co = nt * 16 + (lane & 15), ci = kc * 32 + (lane >> 4) * 8 + j;
        wgt[local] = __float2bfloat16(w_g1[(co * 64 + ci) * 9 + tap]);
    } else if (idx < 117760) {
        int local = idx - 110592;
        int co = local >> 6, ci = local & 63;
        float a = co < 100 ? w_kp[co * 64 + ci] : 0.f;
        float b = co < 100 ? w_g2[co * 64 + ci] : 0.f;
        wkpt[local] = __float2bfloat16(a);
        wg2t[local] = __float2bfloat16(b);
    }
}

// ---------------- conv1: half-row blocks (32 px), 4 blocks/CU ----------------
__global__ __launch_bounds__(256, 4) void conv1_tiled(
    const float* __restrict__ x, const __hip_bfloat16* __restrict__ wb,
    const float* __restrict__ bias, const float* __restrict__ gamma,
    const float* __restrict__ beta, const float* __restrict__ mean,
    const float* __restrict__ var, __hip_bfloat16* __restrict__ outp)
{
    constexpr int KC = 4, CINP = 132;
    __shared__ short xs[3 * 34 * CINP];   // 26,928 B
    const int blk = blockIdx.x;
    const int half = blk & 1, h = (blk >> 1) & 63, n = blk >> 7;
    const int w0 = half * 32;             // source col base of this 32-px slab
    const int tid = threadIdx.x;
    const int lane = tid & 63, wave = tid >> 6;
    const int m = lane & 15, q = lane >> 4;
    const int mp = wave & 1, np = wave >> 1;   // np in [0,2)

    // zero the single invalid border column (lc=0 for half0: src=-1;
    // lc=33 for half1: src=64), all 3 rows, 128 ch
    if (tid < 48) {
        int c8 = tid & 15, r = tid >> 4;
        int lc = half ? 33 : 0;
        *(short8*)&xs[(r * 34 + lc) * CINP + c8 * 8] = (short8){0, 0, 0, 0, 0, 0, 0, 0};
    }
    // main staging: 3 rows x 64 ci2 x 9 aligned spans = 1728 tasks
    const int B = half ? 28 : 0;          // first aligned source col of the spans
    for (int idx = tid; idx < 1728; idx += 256) {
        int w4 = idx % 9;
        int rest = idx / 9;
        int ci2 = rest & 63, r = rest >> 6;
        int ci = ci2 * 2;
        int sr = h + r - 1;
        int sc0 = B + w4 * 4;             // source col of d=0 (always in [0,60])
        f32x4 v0 = {0.f, 0.f, 0.f, 0.f}, v1 = {0.f, 0.f, 0.f, 0.f};
        if ((unsigned)sr < 64u) {
            const float* xp0 = &x[((n * 128 + ci) * 64 + sr) * 64 + sc0];
            v0 = *(const f32x4*)xp0;
            v1 = *(const f32x4*)(xp0 + 4096);
        }
        #pragma unroll
        for (int d = 0; d < 4; ++d) {
            int lc = sc0 + d - w0 + 1;    // padded-local col
            if ((unsigned)lc < 34u) {
                int pk = (int)(unsigned short)bf16_bits(v0[d]) |
                         ((int)(unsigned short)bf16_bits(v1[d]) << 16);
                *(int*)&xs[(r * 34 + lc) * CINP + ci] = pk;
            }
        }
    }
    __syncthreads();

    f32x4 acc0 = {0.f, 0.f, 0.f, 0.f}, acc1 = {0.f, 0.f, 0.f, 0.f};
    const short* wgb = (const short*)wb + lane * 8;
    const int arow = mp * 16 + m;         // local px row

    #pragma unroll
    for (int kh = 0; kh < 3; ++kh) {
        #pragma unroll
        for (int kw = 0; kw < 3; ++kw) {
            #pragma unroll
            for (int kc = 0; kc < KC; ++kc) {
                const short* ap = &xs[(kh * 34 + arow + kw) * CINP + kc * 32 + q * 8];
                short8 a0 = *(const short8*)ap;
                const int tap = kh * 3 + kw;
                const short* bp = wgb + (((tap * KC + kc) * 4 + np * 2) << 9);
                short8 b0 = *(const short8*)bp;
                short8 b1 = *(const short8*)(bp + 512);
                acc0 = __builtin_amdgcn_mfma_f32_16x16x32_bf16(a0, b0, acc0, 0, 0, 0);
                acc1 = __builtin_amdgcn_mfma_f32_16x16x32_bf16(a0, b1, acc1, 0, 0, 0);
            }
        }
    }

    float scv[2], shv[2];
    #pragma unroll
    for (int j = 0; j < 2; ++j) {
        const int c = np * 32 + j * 16 + m;
        float inv = rsqrtf(var[c] + 1e-5f);
        scv[j] = gamma[c] * inv;
        shv[j] = (bias[c] - mean[c]) * scv[j] + beta[c];
    }
    const f32x4* accs[2] = {&acc0, &acc1};
    #pragma unroll
    for (int j = 0; j < 2; ++j) {
        const int c = np * 32 + j * 16 + m;
        const f32x4 a = *accs[j];
        #pragma unroll
        for (int r = 0; r < 4; ++r) {
            const int px = w0 + mp * 16 + q * 4 + r;
            float ov = fmaxf(fmaf(a[r], scv[j], shv[j]), 0.f);
            outp[(((n * 66 + h + 1) * 66) + px + 1) * 64 + c] = __float2bfloat16(ov);
        }
    }
}

// ---------------- fused conv2 + predictor + softmax + reassembly (R19) ----------------
__global__ __launch_bounds__(256, 2) void conv2_reassembly(
    const __hip_bfloat16* __restrict__ cbf, const __hip_bfloat16* __restrict__ wb,
    const float* __restrict__ b_g1,
    const __hip_bfloat16* __restrict__ wkpt, const __hip_bfloat16* __restrict__ wg2t,
    const float* __restrict__ bkp, const float* __restrict__ bg2,
    const float* __restrict__ x, float* __restrict__ out)
{
    constexpr int CIN = 64, KC = 2, NC8 = 8, CINP = 68;
    // union carve: phase1 = xs(26928B)+g1s(8704B); phase2 = kls(25600B)+xls(21760B)
    __shared__ __align__(16) char smem[47360];
    short* xs  = (short*)smem;                  // [3*66][68]
    short* g1s = (short*)(smem + 26928);        // [64][68]
    float (*kls)[4][64] = (float(*)[4][64])smem;           // [25][4][64]
    float (*xls)[5][68] = (float(*)[5][68])(smem + 25600); // [16][5][68]

    const int blk = blockIdx.x, h = blk & 63, n = blk >> 6;
    const int tid = threadIdx.x;
    const int lane = tid & 63, wave = tid >> 6;
    const int m = lane & 15, q = lane >> 4;

    // stage content rows h..h+2 (padded coords); zero the border pixels
    const short* xg = (const short*)cbf + ((n * 66 + h) * 66) * CIN;
    for (int idx = tid; idx < 3 * 66 * NC8; idx += 256) {
        int p = idx >> 3;
        int c8 = idx & 7;
        int r = (p >= 132) ? 2 : (p >= 66 ? 1 : 0);
        int col = p - r * 66;
        int pr = h + r;
        short8 v = *(const short8*)(xg + idx * 8);
        if (pr == 0 || pr == 65 || col == 0 || col == 65)
            v = (short8){0, 0, 0, 0, 0, 0, 0, 0};
        *(short8*)&xs[p * CINP + c8 * 8] = v;
    }
    __syncthreads();

    // ---- phase A: conv2 ----
    {
        const int mp = wave & 1, np = wave >> 1;
        f32x4 acc00 = {0.f, 0.f, 0.f, 0.f}, acc01 = {0.f, 0.f, 0.f, 0.f};
        f32x4 acc10 = {0.f, 0.f, 0.f, 0.f}, acc11 = {0.f, 0.f, 0.f, 0.f};
        const short* wgb = (const short*)wb + lane * 8;
        const int arow = mp * 32 + m;
        #pragma unroll
        for (int kh = 0; kh < 3; ++kh) {
            #pragma unroll
            for (int kw = 0; kw < 3; ++kw) {
                #pragma unroll
                for (int kc = 0; kc < KC; ++kc) {
                    const short* ap = &xs[(kh * 66 + arow + kw) * CINP + kc * 32 + q * 8];
                    short8 a0 = *(const short8*)ap;
                    short8 a1 = *(const short8*)(ap + 16 * CINP);
                    const int tap = kh * 3 + kw;
                    const short* bp = wgb + (((tap * KC + kc) * 4 + np * 2) << 9);
                    short8 b0 = *(const short8*)bp;
                    short8 b1 = *(const short8*)(bp + 512);
                    acc00 = __builtin_amdgcn_mfma_f32_16x16x32_bf16(a0, b0, acc00, 0, 0, 0);
                    acc01 = __builtin_amdgcn_mfma_f32_16x16x32_bf16(a0, b1, acc01, 0, 0, 0);
                    acc10 = __builtin_amdgcn_mfma_f32_16x16x32_bf16(a1, b0, acc10, 0, 0, 0);
                    acc11 = __builtin_amdgcn_mfma_f32_16x16x32_bf16(a1, b1, acc11, 0, 0, 0);
                }
            }
        }
        const f32x4* accs[2][2] = {{&acc00, &acc01}, {&acc10, &acc11}};
        #pragma unroll
        for (int i = 0; i < 2; ++i) {
            #pragma unroll
            for (int j = 0; j < 2; ++j) {
                const int c = np * 32 + j * 16 + m;
                const float bb = b_g1[c];
                const f32x4 a = *accs[i][j];
                #pragma unroll
                for (int r = 0; r < 4; ++r) {
                    const int px = mp * 32 + i * 16 + q * 4 + r;
                    float ov = fmaxf(a[r] + bb, 0.f);
                    g1s[px * 68 + c] = bf16_bits(ov);
                }
            }
        }
    }
    __syncthreads();

    // ---- phase B: predictor GEMMs, wave = m-tile ----
    const int mt = wave;
    const short* aK = &xs[(66 + 1 + mt * 16 + m) * CINP];
    const short* aG = &g1s[(mt * 16 + m) * 68];
    const short* BK = (const short*)wkpt + m * 64;
    const short* BG = (const short*)wg2t + m * 64;

    f32x4 kacc[7], gacc[7];
    #pragma unroll
    for (int nt = 0; nt < 7; ++nt) {
        kacc[nt] = (f32x4){0.f, 0.f, 0.f, 0.f};
        gacc[nt] = (f32x4){0.f, 0.f, 0.f, 0.f};
    }
    #pragma unroll
    for (int ks = 0; ks < 2; ++ks) {
        short8 ak = *(const short8*)(aK + ks * 32 + q * 8);
        short8 ag = *(const short8*)(aG + ks * 32 + q * 8);
        #pragma unroll
        for (int nt = 0; nt < 7; ++nt) {
            short8 bk = *(const short8*)(BK + nt * 1024 + ks * 32 + q * 8);
            short8 bg = *(const short8*)(BG + nt * 1024 + ks * 32 + q * 8);
            kacc[nt] = __builtin_amdgcn_mfma_f32_16x16x32_bf16(ak, bk, kacc[nt], 0, 0, 0);
            gacc[nt] = __builtin_amdgcn_mfma_f32_16x16x32_bf16(ag, bg, gacc[nt], 0, 0, 0);
        }
    }

    float p[7][4];
    float mxr[4] = {-1e30f, -1e30f, -1e30f, -1e30f};
    #pragma unroll
    for (int nt = 0; nt < 7; ++nt) {
        const int co = nt * 16 + m;
        const bool valid = co < 100;
        const float bk = valid ? bkp[co] : 0.f;
        const float bg = valid ? bg2[co] : 0.f;
        #pragma unroll
        for (int r = 0; r < 4; ++r) {
            float ka = kacc[nt][r] + bk;
            float ga = gacc[nt][r] + bg;
            float v = valid ? ka * (1.f / (1.f + __expf(-ga))) : -1e30f;
            p[nt][r] = v;
            mxr[r] = fmaxf(mxr[r], v);
        }
    }
    #pragma unroll
    for (int msk = 1; msk <= 8; msk <<= 1) {
        #pragma unroll
        for (int r = 0; r < 4; ++r)
            mxr[r] = fmaxf(mxr[r], __shfl_xor(mxr[r], msk, 64));
    }
    float sr[4] = {0.f, 0.f, 0.f, 0.f};
    #pragma unroll
    for (int nt = 0; nt < 7; ++nt) {
        #pragma unroll
        for (int r = 0; r < 4; ++r) {
            p[nt][r] = __expf(p[nt][r] - mxr[r]);
            sr[r] += p[nt][r];
        }
    }
    #pragma unroll
    for (int msk = 1; msk <= 8; msk <<= 1) {
        #pragma unroll
        for (int r = 0; r < 4; ++r)
            sr[r] += __shfl_xor(sr[r], msk, 64);
    }
    float rinv[4];
    #pragma unroll
    for (int r = 0; r < 4; ++r) rinv[r] = 1.f / sr[r];

    // ---- phase C: ker row -> LDS (xs/g1s dead after this barrier) ----
    __syncthreads();
    #pragma unroll
    for (int nt = 0; nt < 7; ++nt) {
        const int co = nt * 16 + m;
        if (co < 100) {
            const int tap = co >> 2, quad = co & 3;
            #pragma unroll
            for (int r = 0; r < 4; ++r) {
                const int px = mt * 16 + q * 4 + r;
                kls[tap][quad][px] = p[nt][r] * rinv[r];
            }
        }
    }

    // ---- T14 prefetch machinery ----
    const int w = tid & 63, cg = tid >> 6;
    f32x4 pf[5];
    float pel = 0.f, per_ = 0.f;
    auto prefetch = [&](int c0v) {
        const float* xb = &x[(size_t)(n * 128 + c0v) * 4096];
        #pragma unroll
        for (int k = 0; k < 5; ++k) {
            int idx = tid + k * 256;
            int c = idx / 80, r2 = idx % 80;
            int rr = r2 / 16, c4 = r2 % 16;
            int srr = min(max(h - 2 + rr, 0), 63);
            pf[k] = *(const f32x4*)&xb[c * 4096 + srr * 64 + c4 * 4];
        }
        if (tid < 80) {
            int c = tid / 5, rr = tid % 5;
            int srr = min(max(h - 2 + rr, 0), 63);
            pel  = xb[c * 4096 + srr * 64 + 0];
            per_ = xb[c * 4096 + srr * 64 + 63];
        }
    };
    auto commit = [&]() {
        #pragma unroll
        for (int k = 0; k < 5; ++k) {
            int idx = tid + k * 256;
            int c = idx / 80, r2 = idx % 80;
            int rr = r2 / 16, c4 = r2 % 16;
            *(float2*)&xls[c][rr][2 + c4 * 4] = make_float2(pf[k][0], pf[k][1]);
            *(float2*)&xls[c][rr][4 + c4 * 4] = make_float2(pf[k][2], pf[k][3]);
        }
        if (tid < 80) {
            int c = tid / 5, rr = tid % 5;
            xls[c][rr][0] = pel;  xls[c][rr][1] = pel;
            xls[c][rr][66] = per_; xls[c][rr][67] = per_;
        }
    };

    prefetch(0);       // chunk-0 loads overlap the kls writes above
    commit();          // land them (xls not read before the next barrier)
    __syncthreads();

    // ---- phase D: 8 channel chunks; prefetch(c+1) hidden under compute ----
    for (int chunk = 0; ; ++chunk) {
        if (chunk < 7) prefetch((chunk + 1) * 16);
        const int c0 = chunk * 16;
        float4 acc[4] = {{0.f, 0.f, 0.f, 0.f}, {0.f, 0.f, 0.f, 0.f},
                         {0.f, 0.f, 0.f, 0.f}, {0.f, 0.f, 0.f, 0.f}};
        #pragma unroll
        for (int i = 0; i < 5; ++i) {
            #pragma unroll
            for (int j = 0; j < 5; ++j) {
                const int t = i * 5 + j;
                const float kx = kls[t][0][w];
                const float ky = kls[t][1][w];
                const float kz = kls[t][2][w];
                const float kw_ = kls[t][3][w];
                #pragma unroll
                for (int cc = 0; cc < 4; ++cc) {
                    const float xv = xls[cg * 4 + cc][i][w + j];
                    acc[cc].x = fmaf(xv, kx, acc[cc].x);
                    acc[cc].y = fmaf(xv, ky, acc[cc].y);
                    acc[cc].z = fmaf(xv, kz, acc[cc].z);
                    acc[cc].w = fmaf(xv, kw_, acc[cc].w);
                }
            }
        }
        #pragma unroll
        for (int cc = 0; cc < 4; ++cc) {
            const int c = c0 + cg * 4 + cc;
            *(float2*)&out[((n * 128 + c) * 128 + 2 * h + 0) * 128 + 2 * w] =
                make_float2(acc[cc].x, acc[cc].y);
            *(float2*)&out[((n * 128 + c) * 128 + 2 * h + 1) * 128 + 2 * w] =
                make_float2(acc[cc].z, acc[cc].w);
        }
        if (chunk == 7) break;
        __syncthreads();   // all reads of xls done
        commit();          // land prefetched chunk
        __syncthreads();   // xls ready
    }
}

extern "C" void kernel_launch(void* const* d_in, const int* in_sizes, int n_in,
                              void* d_out, int out_size, void* d_ws, size_t ws_size,
                              hipStream_t stream) {
    const float* x     = (const float*)d_in[0];
    const float* w_enc = (const float*)d_in[1];
    const float* b_enc = (const float*)d_in[2];
    const float* gamma = (const float*)d_in[3];
    const float* beta  = (const float*)d_in[4];
    const float* mean  = (const float*)d_in[5];
    const float* var   = (const float*)d_in[6];
    const float* w_kp  = (const float*)d_in[7];
    const float* b_kp  = (const float*)d_in[8];
    const float* w_g1  = (const float*)d_in[9];
    const float* b_g1  = (const float*)d_in[10];
    const float* w_g2  = (const float*)d_in[11];
    const float* b_g2  = (const float*)d_in[12];
    float* out = (float*)d_out;

    // ws carve (ker eliminated)
    __hip_bfloat16* cbf  = (__hip_bfloat16*)d_ws;            // (N,66,66,64) bf16
    __hip_bfloat16* wtt  = cbf + 2230272;                    // conv1 B-frags (73728)
    __hip_bfloat16* wgt  = wtt + 73728;                      // conv2 B-frags (36864)
    __hip_bfloat16* wkpt = wgt + 36864;                      // [112][64] bf16
    __hip_bfloat16* wg2t = wkpt + 7168;                      // [112][64] bf16

    w_all<<<460, 256, 0, stream>>>(w_enc, w_g1, w_kp, w_g2, wtt, wgt, wkpt, wg2t);
    conv1_tiled<<<1024, 256, 0, stream>>>(
        x, wtt, b_enc, gamma, beta, mean, var, cbf);
    conv2_reassembly<<<512, 256, 0, stream>>>(
        cbf, wgt, b_g1, wkpt, wg2t, b_kp, b_g2, x, out);
}

// Round 18
// 162.468 us; speedup vs baseline: 1.2614x; 1.0367x over previous
//
#include <hip/hip_runtime.h>
#include <hip/hip_bf16.h>

// CARAFE-style SAU. Round 23: R19b config + double-buffered xls in phase D.
//  - R22's conv1 half-row split regressed (-6us); conv1 reverted to R19.
//  - conv2_reassembly is grid-limited at 2 blocks/CU -> LDS is free: grow
//    phase-2 to kls + 2x xls (69.1 KB) and drop the WAR barrier. Phase D:
//    15 -> 8 barriers, same block shape/VGPR/layouts (ptr-swap buffers).
//  - FMA order/operands bit-identical (absmax must stay 0.001953125).
// N=8, Cin=128, H=W=64, Cmid=64, NK=100, K=5, S=2.

typedef __attribute__((ext_vector_type(8))) short short8;
typedef __attribute__((ext_vector_type(4))) float f32x4;

static __device__ __forceinline__ short bf16_bits(float v) {
    __hip_bfloat16 h = __float2bfloat16(v);
    return __builtin_bit_cast(short, h);
}

// ---------------- merged weight prep ----------------
__global__ void w_all(const float* __restrict__ w_enc, const float* __restrict__ w_g1,
                      const float* __restrict__ w_kp, const float* __restrict__ w_g2,
                      __hip_bfloat16* __restrict__ wtt, __hip_bfloat16* __restrict__ wgt,
                      __hip_bfloat16* __restrict__ wkpt, __hip_bfloat16* __restrict__ wg2t) {
    int idx = blockIdx.x * 256 + threadIdx.x;
    if (idx < 73728) {
        int j = idx & 7, lane = (idx >> 3) & 63, nt = (idx >> 9) & 3, rest = idx >> 11;
        int kc = rest & 3, tap = rest >> 2;
        int co = nt * 16 + (lane & 15), ci = kc * 32 + (lane >> 4) * 8 + j;
        wtt[idx] = __float2bfloat16(w_enc[(co * 128 + ci) * 9 + tap]);
    } else if (idx < 110592) {
        int local = idx - 73728;
        int j = local & 7, lane = (local >> 3) & 63, nt = (local >> 9) & 3, rest = local >> 11;
        int kc = rest & 1, tap = rest >> 1;
        int co = nt * 16 + (lane & 15), ci = kc * 32 + (lane >> 4) * 8 + j;
        wgt[local] = __float2bfloat16(w_g1[(co * 64 + ci) * 9 + tap]);
    } else if (idx < 117760) {
        int local = idx - 110592;
        int co = local >> 6, ci = local & 63;
        float a = co < 100 ? w_kp[co * 64 + ci] : 0.f;
        float b = co < 100 ? w_g2[co * 64 + ci] : 0.f;
        wkpt[local] = __float2bfloat16(a);
        wg2t[local] = __float2bfloat16(b);
    }
}

// ---------------- conv1: stage f32 x directly, single-barrier MFMA (R19) ----------------
__global__ __launch_bounds__(256, 2) void conv1_tiled(
    const float* __restrict__ x, const __hip_bfloat16* __restrict__ wb,
    const float* __restrict__ bias, const float* __restrict__ gamma,
    const float* __restrict__ beta, const float* __restrict__ mean,
    const float* __restrict__ var, __hip_bfloat16* __restrict__ outp)
{
    constexpr int CIN = 128, KC = 4, CINP = 132;
    __shared__ short xs[3 * 66 * CINP];
    const int blk = blockIdx.x, h = blk & 63, n = blk >> 6;
    const int tid = threadIdx.x;
    const int lane = tid & 63, wave = tid >> 6;
    const int m = lane & 15, q = lane >> 4;
    const int mp = wave & 1, np = wave >> 1;

    if (tid < 96) {
        int c8 = tid & 15, side = (tid >> 4) & 1, r = tid >> 5;
        int col = side ? 65 : 0;
        *(short8*)&xs[(r * 66 + col) * CINP + c8 * 8] = (short8){0, 0, 0, 0, 0, 0, 0, 0};
    }
    for (int idx = tid; idx < 3072; idx += 256) {
        int w4 = idx & 15, ci2 = (idx >> 4) & 63, r = idx >> 10;
        int ci = ci2 * 2;
        int sr = h + r - 1;
        f32x4 v0 = {0.f, 0.f, 0.f, 0.f}, v1 = {0.f, 0.f, 0.f, 0.f};
        if ((unsigned)sr < 64u) {
            const float* xp0 = &x[((n * 128 + ci) * 64 + sr) * 64 + w4 * 4];
            v0 = *(const f32x4*)xp0;
            v1 = *(const f32x4*)(xp0 + 4096);
        }
        short* dst = &xs[(r * 66 + 1 + w4 * 4) * CINP + ci];
        #pragma unroll
        for (int d = 0; d < 4; ++d) {
            int pk = (int)(unsigned short)bf16_bits(v0[d]) |
                     ((int)(unsigned short)bf16_bits(v1[d]) << 16);
            *(int*)(dst + d * CINP) = pk;
        }
    }
    __syncthreads();

    f32x4 acc00 = {0.f, 0.f, 0.f, 0.f}, acc01 = {0.f, 0.f, 0.f, 0.f};
    f32x4 acc10 = {0.f, 0.f, 0.f, 0.f}, acc11 = {0.f, 0.f, 0.f, 0.f};
    const short* wgb = (const short*)wb + lane * 8;
    const int arow = mp * 32 + m;

    #pragma unroll
    for (int kh = 0; kh < 3; ++kh) {
        #pragma unroll
        for (int kw = 0; kw < 3; ++kw) {
            #pragma unroll
            for (int kc = 0; kc < KC; ++kc) {
                const short* ap = &xs[(kh * 66 + arow + kw) * CINP + kc * 32 + q * 8];
                short8 a0 = *(const short8*)ap;
                short8 a1 = *(const short8*)(ap + 16 * CINP);
                const int tap = kh * 3 + kw;
                const short* bp = wgb + (((tap * KC + kc) * 4 + np * 2) << 9);
                short8 b0 = *(const short8*)bp;
                short8 b1 = *(const short8*)(bp + 512);
                acc00 = __builtin_amdgcn_mfma_f32_16x16x32_bf16(a0, b0, acc00, 0, 0, 0);
                acc01 = __builtin_amdgcn_mfma_f32_16x16x32_bf16(a0, b1, acc01, 0, 0, 0);
                acc10 = __builtin_amdgcn_mfma_f32_16x16x32_bf16(a1, b0, acc10, 0, 0, 0);
                acc11 = __builtin_amdgcn_mfma_f32_16x16x32_bf16(a1, b1, acc11, 0, 0, 0);
            }
        }
    }

    float scv[2], shv[2];
    #pragma unroll
    for (int j = 0; j < 2; ++j) {
        const int c = np * 32 + j * 16 + m;
        float inv = rsqrtf(var[c] + 1e-5f);
        scv[j] = gamma[c] * inv;
        shv[j] = (bias[c] - mean[c]) * scv[j] + beta[c];
    }
    const f32x4* accs[2][2] = {{&acc00, &acc01}, {&acc10, &acc11}};
    #pragma unroll
    for (int i = 0; i < 2; ++i) {
        #pragma unroll
        for (int j = 0; j < 2; ++j) {
            const int c = np * 32 + j * 16 + m;
            const f32x4 a = *accs[i][j];
            #pragma unroll
            for (int r = 0; r < 4; ++r) {
                const int px = mp * 32 + i * 16 + q * 4 + r;
                float ov = fmaxf(fmaf(a[r], scv[j], shv[j]), 0.f);
                outp[(((n * 66 + h + 1) * 66) + px + 1) * 64 + c] = __float2bfloat16(ov);
            }
        }
    }
}

// ---------------- fused conv2 + predictor + softmax + reassembly ----------------
__global__ __launch_bounds__(256, 2) void conv2_reassembly(
    const __hip_bfloat16* __restrict__ cbf, const __hip_bfloat16* __restrict__ wb,
    const float* __restrict__ b_g1,
    const __hip_bfloat16* __restrict__ wkpt, const __hip_bfloat16* __restrict__ wg2t,
    const float* __restrict__ bkp, const float* __restrict__ bg2,
    const float* __restrict__ x, float* __restrict__ out)
{
    constexpr int CIN = 64, KC = 2, NC8 = 8, CINP = 68;
    // union carve: phase1 = xs(26928B)+g1s(8704B)=35632B;
    // phase2 = kls(25600B) + xls0(21760B) + xls1(21760B) = 69120B
    __shared__ __align__(16) char smem[69120];
    short* xs  = (short*)smem;                  // [3*66][68]
    short* g1s = (short*)(smem + 26928);        // [64][68]
    float (*kls)[4][64]  = (float(*)[4][64])smem;            // [25][4][64]
    float (*xbuf0)[5][68] = (float(*)[5][68])(smem + 25600); // [16][5][68]
    float (*xbuf1)[5][68] = (float(*)[5][68])(smem + 47360); // [16][5][68]

    const int blk = blockIdx.x, h = blk & 63, n = blk >> 6;
    const int tid = threadIdx.x;
    const int lane = tid & 63, wave = tid >> 6;
    const int m = lane & 15, q = lane >> 4;

    // stage content rows h..h+2 (padded coords); zero the border pixels
    const short* xg = (const short*)cbf + ((n * 66 + h) * 66) * CIN;
    for (int idx = tid; idx < 3 * 66 * NC8; idx += 256) {
        int p = idx >> 3;
        int c8 = idx & 7;
        int r = (p >= 132) ? 2 : (p >= 66 ? 1 : 0);
        int col = p - r * 66;
        int pr = h + r;
        short8 v = *(const short8*)(xg + idx * 8);
        if (pr == 0 || pr == 65 || col == 0 || col == 65)
            v = (short8){0, 0, 0, 0, 0, 0, 0, 0};
        *(short8*)&xs[p * CINP + c8 * 8] = v;
    }
    __syncthreads();

    // ---- phase A: conv2 ----
    {
        const int mp = wave & 1, np = wave >> 1;
        f32x4 acc00 = {0.f, 0.f, 0.f, 0.f}, acc01 = {0.f, 0.f, 0.f, 0.f};
        f32x4 acc10 = {0.f, 0.f, 0.f, 0.f}, acc11 = {0.f, 0.f, 0.f, 0.f};
        const short* wgb = (const short*)wb + lane * 8;
        const int arow = mp * 32 + m;
        #pragma unroll
        for (int kh = 0; kh < 3; ++kh) {
            #pragma unroll
            for (int kw = 0; kw < 3; ++kw) {
                #pragma unroll
                for (int kc = 0; kc < KC; ++kc) {
                    const short* ap = &xs[(kh * 66 + arow + kw) * CINP + kc * 32 + q * 8];
                    short8 a0 = *(const short8*)ap;
                    short8 a1 = *(const short8*)(ap + 16 * CINP);
                    const int tap = kh * 3 + kw;
                    const short* bp = wgb + (((tap * KC + kc) * 4 + np * 2) << 9);
                    short8 b0 = *(const short8*)bp;
                    short8 b1 = *(const short8*)(bp + 512);
                    acc00 = __builtin_amdgcn_mfma_f32_16x16x32_bf16(a0, b0, acc00, 0, 0, 0);
                    acc01 = __builtin_amdgcn_mfma_f32_16x16x32_bf16(a0, b1, acc01, 0, 0, 0);
                    acc10 = __builtin_amdgcn_mfma_f32_16x16x32_bf16(a1, b0, acc10, 0, 0, 0);
                    acc11 = __builtin_amdgcn_mfma_f32_16x16x32_bf16(a1, b1, acc11, 0, 0, 0);
                }
            }
        }
        const f32x4* accs[2][2] = {{&acc00, &acc01}, {&acc10, &acc11}};
        #pragma unroll
        for (int i = 0; i < 2; ++i) {
            #pragma unroll
            for (int j = 0; j < 2; ++j) {
                const int c = np * 32 + j * 16 + m;
                const float bb = b_g1[c];
                const f32x4 a = *accs[i][j];
                #pragma unroll
                for (int r = 0; r < 4; ++r) {
                    const int px = mp * 32 + i * 16 + q * 4 + r;
                    float ov = fmaxf(a[r] + bb, 0.f);
                    g1s[px * 68 + c] = bf16_bits(ov);
                }
            }
        }
    }
    __syncthreads();

    // ---- phase B: predictor GEMMs, wave = m-tile ----
    const int mt = wave;
    const short* aK = &xs[(66 + 1 + mt * 16 + m) * CINP];
    const short* aG = &g1s[(mt * 16 + m) * 68];
    const short* BK = (const short*)wkpt + m * 64;
    const short* BG = (const short*)wg2t + m * 64;

    f32x4 kacc[7], gacc[7];
    #pragma unroll
    for (int nt = 0; nt < 7; ++nt) {
        kacc[nt] = (f32x4){0.f, 0.f, 0.f, 0.f};
        gacc[nt] = (f32x4){0.f, 0.f, 0.f, 0.f};
    }
    #pragma unroll
    for (int ks = 0; ks < 2; ++ks) {
        short8 ak = *(const short8*)(aK + ks * 32 + q * 8);
        short8 ag = *(const short8*)(aG + ks * 32 + q * 8);
        #pragma unroll
        for (int nt = 0; nt < 7; ++nt) {
            short8 bk = *(const short8*)(BK + nt * 1024 + ks * 32 + q * 8);
            short8 bg = *(const short8*)(BG + nt * 1024 + ks * 32 + q * 8);
            kacc[nt] = __builtin_amdgcn_mfma_f32_16x16x32_bf16(ak, bk, kacc[nt], 0, 0, 0);
            gacc[nt] = __builtin_amdgcn_mfma_f32_16x16x32_bf16(ag, bg, gacc[nt], 0, 0, 0);
        }
    }

    float p[7][4];
    float mxr[4] = {-1e30f, -1e30f, -1e30f, -1e30f};
    #pragma unroll
    for (int nt = 0; nt < 7; ++nt) {
        const int co = nt * 16 + m;
        const bool valid = co < 100;
        const float bk = valid ? bkp[co] : 0.f;
        const float bg = valid ? bg2[co] : 0.f;
        #pragma unroll
        for (int r = 0; r < 4; ++r) {
            float ka = kacc[nt][r] + bk;
            float ga = gacc[nt][r] + bg;
            float v = valid ? ka * (1.f / (1.f + __expf(-ga))) : -1e30f;
            p[nt][r] = v;
            mxr[r] = fmaxf(mxr[r], v);
        }
    }
    #pragma unroll
    for (int msk = 1; msk <= 8; msk <<= 1) {
        #pragma unroll
        for (int r = 0; r < 4; ++r)
            mxr[r] = fmaxf(mxr[r], __shfl_xor(mxr[r], msk, 64));
    }
    float sr[4] = {0.f, 0.f, 0.f, 0.f};
    #pragma unroll
    for (int nt = 0; nt < 7; ++nt) {
        #pragma unroll
        for (int r = 0; r < 4; ++r) {
            p[nt][r] = __expf(p[nt][r] - mxr[r]);
            sr[r] += p[nt][r];
        }
    }
    #pragma unroll
    for (int msk = 1; msk <= 8; msk <<= 1) {
        #pragma unroll
        for (int r = 0; r < 4; ++r)
            sr[r] += __shfl_xor(sr[r], msk, 64);
    }
    float rinv[4];
    #pragma unroll
    for (int r = 0; r < 4; ++r) rinv[r] = 1.f / sr[r];

    // ---- phase C: ker row -> LDS (xs/g1s dead after this barrier) ----
    __syncthreads();
    #pragma unroll
    for (int nt = 0; nt < 7; ++nt) {
        const int co = nt * 16 + m;
        if (co < 100) {
            const int tap = co >> 2, quad = co & 3;
            #pragma unroll
            for (int r = 0; r < 4; ++r) {
                const int px = mt * 16 + q * 4 + r;
                kls[tap][quad][px] = p[nt][r] * rinv[r];
            }
        }
    }

    // ---- T14 prefetch machinery ----
    const int w = tid & 63, cg = tid >> 6;
    f32x4 pf[5];
    float pel = 0.f, per_ = 0.f;
    auto prefetch = [&](int c0v) {
        const float* xb = &x[(size_t)(n * 128 + c0v) * 4096];
        #pragma unroll
        for (int k = 0; k < 5; ++k) {
            int idx = tid + k * 256;
            int c = idx / 80, r2 = idx % 80;
            int rr = r2 / 16, c4 = r2 % 16;
            int srr = min(max(h - 2 + rr, 0), 63);
            pf[k] = *(const f32x4*)&xb[c * 4096 + srr * 64 + c4 * 4];
        }
        if (tid < 80) {
            int c = tid / 5, rr = tid % 5;
            int srr = min(max(h - 2 + rr, 0), 63);
            pel  = xb[c * 4096 + srr * 64 + 0];
            per_ = xb[c * 4096 + srr * 64 + 63];
        }
    };
    auto commit = [&](float (*dst)[5][68]) {
        #pragma unroll
        for (int k = 0; k < 5; ++k) {
            int idx = tid + k * 256;
            int c = idx / 80, r2 = idx % 80;
            int rr = r2 / 16, c4 = r2 % 16;
            *(float2*)&dst[c][rr][2 + c4 * 4] = make_float2(pf[k][0], pf[k][1]);
            *(float2*)&dst[c][rr][4 + c4 * 4] = make_float2(pf[k][2], pf[k][3]);
        }
        if (tid < 80) {
            int c = tid / 5, rr = tid % 5;
            dst[c][rr][0] = pel;  dst[c][rr][1] = pel;
            dst[c][rr][66] = per_; dst[c][rr][67] = per_;
        }
    };

    prefetch(0);         // chunk-0 loads overlap the kls writes above
    commit(xbuf0);       // land them (xbuf0 not read before the next barrier)
    __syncthreads();

    // ---- phase D: 8 chunks, double-buffered xls (ONE barrier per chunk) ----
    float (*xcur)[5][68] = xbuf0;
    float (*xnxt)[5][68] = xbuf1;
    for (int chunk = 0; ; ++chunk) {
        if (chunk < 7) prefetch((chunk + 1) * 16);
        const int c0 = chunk * 16;
        float4 acc[4] = {{0.f, 0.f, 0.f, 0.f}, {0.f, 0.f, 0.f, 0.f},
                         {0.f, 0.f, 0.f, 0.f}, {0.f, 0.f, 0.f, 0.f}};
        #pragma unroll
        for (int i = 0; i < 5; ++i) {
            #pragma unroll
            for (int j = 0; j < 5; ++j) {
                const int t = i * 5 + j;
                const float kx = kls[t][0][w];
                const float ky = kls[t][1][w];
                const float kz = kls[t][2][w];
                const float kw_ = kls[t][3][w];
                #pragma unroll
                for (int cc = 0; cc < 4; ++cc) {
                    const float xv = xcur[cg * 4 + cc][i][w + j];
                    acc[cc].x = fmaf(xv, kx, acc[cc].x);
                    acc[cc].y = fmaf(xv, ky, acc[cc].y);
                    acc[cc].z = fmaf(xv, kz, acc[cc].z);
                    acc[cc].w = fmaf(xv, kw_, acc[cc].w);
                }
            }
        }
        #pragma unroll
        for (int cc = 0; cc < 4; ++cc) {
            const int c = c0 + cg * 4 + cc;
            *(float2*)&out[((n * 128 + c) * 128 + 2 * h + 0) * 128 + 2 * w] =
                make_float2(acc[cc].x, acc[cc].y);
            *(float2*)&out[((n * 128 + c) * 128 + 2 * h + 1) * 128 + 2 * w] =
                make_float2(acc[cc].z, acc[cc].w);
        }
        if (chunk == 7) break;
        commit(xnxt);        // write the OTHER buffer (no WAR on xcur)
        __syncthreads();     // xnxt ready for all waves
        float (*tmp)[5][68] = xcur; xcur = xnxt; xnxt = tmp;
    }
}

extern "C" void kernel_launch(void* const* d_in, const int* in_sizes, int n_in,
                              void* d_out, int out_size, void* d_ws, size_t ws_size,
                              hipStream_t stream) {
    const float* x     = (const float*)d_in[0];
    const float* w_enc = (const float*)d_in[1];
    const float* b_enc = (const float*)d_in[2];
    const float* gamma = (const float*)d_in[3];
    const float* beta  = (const float*)d_in[4];
    const float* mean  = (const float*)d_in[5];
    const float* var   = (const float*)d_in[6];
    const float* w_kp  = (const float*)d_in[7];
    const float* b_kp  = (const float*)d_in[8];
    const float* w_g1  = (const float*)d_in[9];
    const float* b_g1  = (const float*)d_in[10];
    const float* w_g2  = (const float*)d_in[11];
    const float* b_g2  = (const float*)d_in[12];
    float* out = (float*)d_out;

    // ws carve (ker eliminated)
    __hip_bfloat16* cbf  = (__hip_bfloat16*)d_ws;            // (N,66,66,64) bf16
    __hip_bfloat16* wtt  = cbf + 2230272;                    // conv1 B-frags (73728)
    __hip_bfloat16* wgt  = wtt + 73728;                      // conv2 B-frags (36864)
    __hip_bfloat16* wkpt = wgt + 36864;                      // [112][64] bf16
    __hip_bfloat16* wg2t = wkpt + 7168;                      // [112][64] bf16

    w_all<<<460, 256, 0, stream>>>(w_enc, w_g1, w_kp, w_g2, wtt, wgt, wkpt, wg2t);
    conv1_tiled<<<512, 256, 0, stream>>>(
        x, wtt, b_enc, gamma, beta, mean, var, cbf);
    conv2_reassembly<<<512, 256, 0, stream>>>(
        cbf, wgt, b_g1, wkpt, wg2t, b_kp, b_g2, x, out);
}